// Round 12
// baseline (47.081 us; speedup 1.0000x reference)
//
#include <hip/hip_runtime.h>
#include <hip/hip_bf16.h>
#include <math.h>

#define HEADS 8
#define DH 32
#define DIM 256
#define INNER 256
#define B_ 2
#define S_ 8
#define H_ 32
#define W_ 16
#define NTOK (B_*S_*H_*W_)   /* 8192 */

// vT: [d][VTPITCH], data at +VTOFF. VTOFF=8 -> 16-token row starts 16B-aligned.
#define VTPITCH (NTOK + 16)
#define VTOFF 8

// attn LDS geometry: block halo = 3 ds x 8 lh rows of 16 tokens (24 krows).
#define KPITCH 40            /* h16 per K token (32 + 8 pad) */

typedef _Float16 h16;
typedef h16 half8 __attribute__((ext_vector_type(8)));
typedef float f32x4 __attribute__((ext_vector_type(4)));

#define QSCALE 0.17677669529663687f   /* 32^-0.5, folded into Q at proj */

// ---------------------------------------------------------------------------
// MFMA f16 GEMM (HW-validated R3+). OUT_MODE: 0=f32 row-major,
// 2=f16 transposed (vT), 3=f16 head-major ([col>>5][row][col&31]).
// ---------------------------------------------------------------------------
#define GBM 128
#define GBN 64
#define GBK 32
#define GPITCH 40

__device__ __forceinline__ uint4 cvt8(const float4 a, const float4 b) {
    union { h16 h[8]; uint4 u; } p;
    p.h[0] = (h16)a.x; p.h[1] = (h16)a.y; p.h[2] = (h16)a.z; p.h[3] = (h16)a.w;
    p.h[4] = (h16)b.x; p.h[5] = (h16)b.y; p.h[6] = (h16)b.z; p.h[7] = (h16)b.w;
    return p.u;
}

template <bool A_F16, int OUT_MODE>
__device__ __forceinline__ void mfma_gemm_tile_t(
    const void* __restrict__ Av, const float* __restrict__ W,
    const float* __restrict__ bias, void* __restrict__ outv,
    int m0, int j0, float oscale, h16* aT, h16* bT)
{
    const int tid  = threadIdx.x;
    const int lane = tid & 63;
    const int wid  = tid >> 6;
    const int wr   = wid >> 1;
    const int wc   = wid & 1;
    const int r    = lane & 15;
    const int g    = lane >> 4;

    f32x4 acc[4][2];
    #pragma unroll
    for (int i = 0; i < 4; ++i)
        #pragma unroll
        for (int j = 0; j < 2; ++j)
            acc[i][j] = (f32x4){0.f, 0.f, 0.f, 0.f};

    const int arow  = tid >> 1;
    const int ahalf = (tid & 1) * 16;
    const int brow  = (tid & 127) >> 1;
    const bool doB  = tid < 128;

    for (int k0 = 0; k0 < DIM; k0 += GBK) {
        if constexpr (A_F16) {
            const h16* A = (const h16*)Av;
            const h16* src = A + (size_t)(m0 + arow) * DIM + k0 + ahalf;
            *(uint4*)(aT + arow * GPITCH + ahalf + 0) = *(const uint4*)(src + 0);
            *(uint4*)(aT + arow * GPITCH + ahalf + 8) = *(const uint4*)(src + 8);
        } else {
            const float* A = (const float*)Av;
            const float* src = A + (size_t)(m0 + arow) * DIM + k0 + ahalf;
            const float4 u0 = *(const float4*)(src + 0);
            const float4 u1 = *(const float4*)(src + 4);
            const float4 u2 = *(const float4*)(src + 8);
            const float4 u3 = *(const float4*)(src + 12);
            *(uint4*)(aT + arow * GPITCH + ahalf + 0) = cvt8(u0, u1);
            *(uint4*)(aT + arow * GPITCH + ahalf + 8) = cvt8(u2, u3);
        }
        if (doB) {
            const float* src = W + (size_t)(j0 + brow) * DIM + k0 + ahalf;
            const float4 u0 = *(const float4*)(src + 0);
            const float4 u1 = *(const float4*)(src + 4);
            const float4 u2 = *(const float4*)(src + 8);
            const float4 u3 = *(const float4*)(src + 12);
            *(uint4*)(bT + brow * GPITCH + ahalf + 0) = cvt8(u0, u1);
            *(uint4*)(bT + brow * GPITCH + ahalf + 8) = cvt8(u2, u3);
        }
        __syncthreads();

        half8 af[4], bf[2];
        #pragma unroll
        for (int fr = 0; fr < 4; ++fr)
            af[fr] = *(const half8*)(aT + (wr * 64 + fr * 16 + r) * GPITCH + g * 8);
        #pragma unroll
        for (int fc = 0; fc < 2; ++fc)
            bf[fc] = *(const half8*)(bT + (wc * 32 + fc * 16 + r) * GPITCH + g * 8);

        #pragma unroll
        for (int fr = 0; fr < 4; ++fr)
            #pragma unroll
            for (int fc = 0; fc < 2; ++fc)
                acc[fr][fc] = __builtin_amdgcn_mfma_f32_16x16x32_f16(
                    af[fr], bf[fc], acc[fr][fc], 0, 0, 0);
        __syncthreads();
    }

    #pragma unroll
    for (int fr = 0; fr < 4; ++fr) {
        #pragma unroll
        for (int fc = 0; fc < 2; ++fc) {
            const int col = j0 + wc * 32 + fc * 16 + r;
            const float badd = bias ? bias[col] : 0.f;
            if constexpr (OUT_MODE == 2) {
                const int rowb = m0 + wr * 64 + fr * 16 + g * 4;
                union { h16 h[4]; uint2 u; } p;
                #pragma unroll
                for (int i = 0; i < 4; ++i) p.h[i] = (h16)(acc[fr][fc][i] * oscale);
                *(uint2*)((h16*)outv + (size_t)col * VTPITCH + VTOFF + rowb) = p.u;
            } else if constexpr (OUT_MODE == 3) {
                const int hd = col >> 5, d = col & 31;
                #pragma unroll
                for (int i = 0; i < 4; ++i) {
                    const int row = m0 + wr * 64 + fr * 16 + g * 4 + i;
                    ((h16*)outv)[((size_t)hd * NTOK + row) * DH + d] =
                        (h16)(acc[fr][fc][i] * oscale);
                }
            } else {
                #pragma unroll
                for (int i = 0; i < 4; ++i) {
                    const int row = m0 + wr * 64 + fr * 16 + g * 4 + i;
                    ((float*)outv)[(size_t)row * INNER + col] =
                        acc[fr][fc][i] * oscale + badd;
                }
            }
        }
    }
}

// ---------------------------------------------------------------------------
// Kernel 1: projections. q (pre-scaled), k -> head-major f16 [2][8][NTOK][32];
// v -> vT f16 [INNER][VTPITCH] (data at +VTOFF).  (unchanged from R11)
// ---------------------------------------------------------------------------
__global__ __launch_bounds__(256) void proj_kernel(
    const float* __restrict__ x, const float* __restrict__ q,
    const float* __restrict__ wq, const float* __restrict__ wk,
    const float* __restrict__ wv, h16* __restrict__ qk, h16* __restrict__ vT)
{
    __shared__ h16 aT[GBM * GPITCH];
    __shared__ h16 bT[GBN * GPITCH];

    const int seg = blockIdx.y >> 2;
    const int jt  = blockIdx.y & 3;
    const float* A = (seg == 0) ? q : x;
    const float* W = (seg == 0) ? wq : ((seg == 1) ? wk : wv);

    if (seg == 2) {
        mfma_gemm_tile_t<false, 2>(A, W, nullptr, vT, blockIdx.x * GBM, jt * GBN,
                                   1.0f, aT, bT);
    } else {
        h16* outp = qk + (size_t)seg * HEADS * NTOK * DH;
        const float sc = (seg == 0) ? QSCALE : 1.0f;
        mfma_gemm_tile_t<false, 3>(A, W, nullptr, outp, blockIdx.x * GBM, jt * GBN,
                                   sc, aT, bT);
    }
}

// ---------------------------------------------------------------------------
// Kernel 2: LDS-K + register-V MFMA local attention.
// grid = (128 tiles, 8 heads), 512 thr = 8 waves.
// vs R11: Vlds DELETED (25 KB) -> LDS ~31 KB -> 4 blocks/CU co-resident
// (thread-capped, 100% wave cap). V fragments come from aligned uint4
// register gathers against vT, issued right after the QK MFMAs so HBM/L3
// latency hides under mask+softmax (R8-validated pattern).
// ---------------------------------------------------------------------------
__global__ __launch_bounds__(512, 4) void attn_kernel(
    const h16* __restrict__ qk, const h16* __restrict__ vT, h16* __restrict__ ao)
{
    __shared__ __align__(16) h16 Klds[24][16][KPITCH];   /* 30720 B */
    __shared__ float ms[8][2][16];                       /* [wave][m,s][q] */

    const int xr   = blockIdx.x;
    const int tile = ((xr & 7) << 4) | (xr >> 3);        // XCD swizzle (128=8*16)
    const int head = blockIdx.y;
    const int tid  = threadIdx.x;
    const int lane = tid & 63;
    const int wid  = __builtin_amdgcn_readfirstlane(tid >> 6);   // 0..7
    const int qr   = wid >> 1;
    const int half = wid & 1;

    const int b = tile >> 6, s = (tile >> 3) & 7, h4b = (tile & 7) * 4;
    const int c = lane & 15, g = lane >> 4;

    const h16* qb = qk + (size_t)head * NTOK * DH;
    const h16* kb = qk + (size_t)(HEADS + head) * NTOK * DH;

    // ---- stage K: wave wid stages krows 3*wid .. 3*wid+2 (1KB each) -------
    #pragma unroll
    for (int kk = 0; kk < 3; ++kk) {
        const int krow = 3 * wid + kk;                 // 0..23
        const int ds = krow >> 3, lh = krow & 7;
        const int s2c = min(max(s + ds - 1, 0), 7);
        const int h2c = min(max(h4b + lh - 2, 0), 31);
        const int tokbase = ((b * 8 + s2c) * 32 + h2c) * 16;
        const int tok = lane >> 2, sl = lane & 3;
        const uint4 v = *(const uint4*)(kb + (size_t)(tokbase + tok) * DH + sl * 8);
        *(uint4*)&Klds[krow][tok][sl * 8] = v;
    }
    __syncthreads();

    // ---- per-run scalars (SALU): runs half*8 .. half*8+7 ------------------
    int   kr[8];
    int   tokvb[8];
    float kill[8];
    #pragma unroll
    for (int rr = 0; rr < 8; ++rr) {
        const int run = half * 8 + rr;                 // 0..15 (15 fictitious)
        const int ds = run / 5, hh = run - 5 * ds;     // ds=3 only for run 15
        const int s2 = s + ds - 1;
        const int h2 = h4b + qr + hh - 2;
        const bool inb = (run < 15) && ((unsigned)s2 < 8u) && ((unsigned)h2 < 32u);
        const int s2c = min(max(s2, 0), 7);
        const int h2c = min(max(h2, 0), 31);
        kr[rr]    = (run < 15) ? (ds * 8 + qr + hh) : 0;
        tokvb[rr] = ((b * 8 + s2c) * 32 + h2c) * 16;   // safe address always
        kill[rr]  = inb ? __builtin_inff() : -1e30f;
    }

    // ---- Q fragment -------------------------------------------------------
    const int n_row = ((b * 8 + s) * 32 + h4b + qr) * 16;
    const half8 qf = *(const half8*)(qb + (size_t)(n_row + c) * DH + g * 8);

    // ---- QK (swapped): dots[rr][i] = S[w2 = 4g+i][q = c] for run rr -------
    f32x4 dots[8];
    #pragma unroll
    for (int rr = 0; rr < 8; ++rr) {
        const half8 kf = *(const half8*)&Klds[kr[rr]][c][g * 8];
        dots[rr] = __builtin_amdgcn_mfma_f32_16x16x32_f16(
            kf, qf, (f32x4){0.f, 0.f, 0.f, 0.f}, 0, 0, 0);
    }

    // ---- prefetch V fragments (overlap with mask/softmax below) -----------
    // chunk ch covers runs 2ch (k 0..15) and 2ch+1 (k 16..31); lane (c,g)
    // needs V^T[d = c / c+16][8 entries]: sel = g>>1 picks the run, off8 =
    // (g&1)*8 the 8-token group. All addresses 16B-aligned.
    union u4h8 { uint4 u4; half8 hv; } vpre0[4], vpre1[4];
    const h16* vrow0 = vT + (size_t)(head * DH + c) * VTPITCH + VTOFF;
    const h16* vrow1 = vrow0 + (size_t)16 * VTPITCH;
    #pragma unroll
    for (int ch = 0; ch < 4; ++ch) {
        const int sel  = g >> 1;
        const int off8 = (g & 1) * 8;
        const int tb   = tokvb[2 * ch + sel] + off8;
        vpre0[ch].u4 = *(const uint4*)(vrow0 + tb);
        vpre1[ch].u4 = *(const uint4*)(vrow1 + tb);
    }

    // ---- mask + max -------------------------------------------------------
    float mx = -1e30f;
    #pragma unroll
    for (int rr = 0; rr < 8; ++rr) {
        const float kl = kill[rr];
        #pragma unroll
        for (int i = 0; i < 4; ++i) {
            const int w2 = 4 * g + i;
            const bool okw = ((unsigned)(w2 - c + 2) <= 4u);   // |w2-c| <= 2
            float dv = okw ? dots[rr][i] : -1e30f;
            dv = fminf(dv, kl);
            dots[rr][i] = dv;
            mx = fmaxf(mx, dv);
        }
    }
    mx = fmaxf(mx, __shfl_xor(mx, 16));
    mx = fmaxf(mx, __shfl_xor(mx, 32));

    // ---- exp + sum + pack (unnormalized P, f16) ---------------------------
    float sum = 0.f;
    int d0[8], d1[8];
    #pragma unroll
    for (int rr = 0; rr < 8; ++rr) {
        const float e0v = __expf(dots[rr][0] - mx);
        const float e1v = __expf(dots[rr][1] - mx);
        const float e2v = __expf(dots[rr][2] - mx);
        const float e3v = __expf(dots[rr][3] - mx);
        sum += (e0v + e1v) + (e2v + e3v);
        union { h16 hh2[2]; int u; } p0, p1;
        p0.hh2[0] = (h16)e0v; p0.hh2[1] = (h16)e1v;
        p1.hh2[0] = (h16)e2v; p1.hh2[1] = (h16)e3v;
        d0[rr] = p0.u; d1[rr] = p1.u;
    }
    sum += __shfl_xor(sum, 16);
    sum += __shfl_xor(sum, 32);

    if (lane < 16) {                     // per-q stats (q = lane)
        ms[wid][0][lane] = mx;
        ms[wid][1][lane] = sum;
    }

    // ---- PV: 4 chunks; A-frag via shfl, B-frag prefetched in regs ---------
    f32x4 o0 = (f32x4){0.f,0.f,0.f,0.f};
    f32x4 o1 = (f32x4){0.f,0.f,0.f,0.f};
    const bool hi = lane >= 32;
    const int l1 = ((lane & 16) ? 32 : 0) + c;
    const int l2 = l1 + 16;

    #pragma unroll
    for (int ch = 0; ch < 4; ++ch) {
        const int w0a = __shfl(d0[2*ch], l1), w0b = __shfl(d0[2*ch+1], l1);
        const int w1a = __shfl(d1[2*ch], l1), w1b = __shfl(d1[2*ch+1], l1);
        const int w2a = __shfl(d0[2*ch], l2), w2b = __shfl(d0[2*ch+1], l2);
        const int w3a = __shfl(d1[2*ch], l2), w3b = __shfl(d1[2*ch+1], l2);
        union { int u[4]; half8 hv; } pf;
        pf.u[0] = hi ? w0b : w0a;
        pf.u[1] = hi ? w1b : w1a;
        pf.u[2] = hi ? w2b : w2a;
        pf.u[3] = hi ? w3b : w3a;

        o0 = __builtin_amdgcn_mfma_f32_16x16x32_f16(pf.hv, vpre0[ch].hv, o0, 0, 0, 0);
        o1 = __builtin_amdgcn_mfma_f32_16x16x32_f16(pf.hv, vpre1[ch].hv, o1, 0, 0, 0);
    }

    // ---- merge halves (obuf aliases Klds; safe after barrier) -------------
    __syncthreads();                     // all LDS K reads done
    float* obuf = (float*)&Klds[0][0][0];   // [4][64][9] floats = 9216 B

    if (half == 1) {
        #pragma unroll
        for (int i = 0; i < 4; ++i) {
            obuf[(qr * 64 + lane) * 9 + i]     = o0[i];
            obuf[(qr * 64 + lane) * 9 + 4 + i] = o1[i];
        }
    }
    __syncthreads();

    if (half == 0) {
        #pragma unroll
        for (int i = 0; i < 4; ++i) {
            const int qi = 4 * g + i;
            const float m_a = ms[wid][0][qi],     s_a = ms[wid][1][qi];
            const float m_b = ms[wid | 1][0][qi], s_b = ms[wid | 1][1][qi];
            const float m  = fmaxf(m_a, m_b);
            const float ea = __expf(m_a - m);
            const float eb = __expf(m_b - m);
            const float den = 1.f / (s_a * ea + s_b * eb);
            const float ob0 = obuf[(qr * 64 + lane) * 9 + i];
            const float ob1 = obuf[(qr * 64 + lane) * 9 + 4 + i];
            const float r0 = (o0[i] * ea + ob0 * eb) * den;
            const float r1 = (o1[i] * ea + ob1 * eb) * den;
            const size_t row = (size_t)(n_row + qi) * INNER + head * DH;
            ao[row + c]      = (h16)r0;
            ao[row + 16 + c] = (h16)r1;
        }
    }
}

// ---------------------------------------------------------------------------
// Kernel 3: out = ao(f16) @ wo^T + bo   grid = (64, 4)   (unchanged)
// ---------------------------------------------------------------------------
__global__ __launch_bounds__(256) void outproj_kernel(
    const h16* __restrict__ ao, const float* __restrict__ wo,
    const float* __restrict__ bo, float* __restrict__ out)
{
    __shared__ h16 aT[GBM * GPITCH];
    __shared__ h16 bT[GBN * GPITCH];
    mfma_gemm_tile_t<true, 0>(ao, wo, bo, out, blockIdx.x * GBM, blockIdx.y * GBN,
                              1.0f, aT, bT);
}

// ---------------------------------------------------------------------------
extern "C" void kernel_launch(void* const* d_in, const int* in_sizes, int n_in,
                              void* d_out, int out_size, void* d_ws, size_t ws_size,
                              hipStream_t stream) {
    const float* x  = (const float*)d_in[0];
    const float* q  = (const float*)d_in[1];
    const float* wq = (const float*)d_in[2];
    const float* wk = (const float*)d_in[3];
    const float* wv = (const float*)d_in[4];
    const float* wo = (const float*)d_in[5];
    const float* bo = (const float*)d_in[6];
    float* out = (float*)d_out;

    // ws: qk f16 [2][8][NTOK][32] (8MB) + vT f16 [INNER][VTPITCH] (4.2MB) + ao (4MB)
    h16* qk = (h16*)d_ws;
    h16* vT = qk + (size_t)2 * HEADS * NTOK * DH;
    h16* ao = vT + (size_t)INNER * VTPITCH;

    dim3 g1(NTOK / GBM, 12);
    proj_kernel<<<g1, 256, 0, stream>>>(x, q, wq, wk, wv, qk, vT);

    dim3 g2(128, HEADS);
    attn_kernel<<<g2, 512, 0, stream>>>(qk, vT, ao);

    dim3 g3(NTOK / GBM, INNER / GBN);
    outproj_kernel<<<g3, 256, 0, stream>>>(ao, wo, bo, out);
}

// Round 13
// 43.447 us; speedup vs baseline: 1.0836x; 1.0836x over previous
//
#include <hip/hip_runtime.h>
#include <hip/hip_bf16.h>
#include <math.h>

#define HEADS 8
#define DH 32
#define DIM 256
#define INNER 256
#define B_ 2
#define S_ 8
#define H_ 32
#define W_ 16
#define NTOK (B_*S_*H_*W_)   /* 8192 */

// blocked V: vTb[head][tokblk(512)][32 d][16 tok] f16 — head stride 262144
#define VHSTRIDE (512*32*16)

typedef _Float16 h16;
typedef h16 half8 __attribute__((ext_vector_type(8)));
typedef float f32x4 __attribute__((ext_vector_type(4)));

#define QSCALE 0.17677669529663687f   /* 32^-0.5, folded into Q at proj */

// ---------------------------------------------------------------------------
// MFMA f16 GEMM (HW-validated R3+). OUT_MODE: 0=f32 row-major,
// 3=f16 head-major ([col>>5][row][col&31]), 4=f16 blocked-V (vTb).
// ---------------------------------------------------------------------------
#define GBM 128
#define GBN 64
#define GBK 32
#define GPITCH 40

__device__ __forceinline__ uint4 cvt8(const float4 a, const float4 b) {
    union { h16 h[8]; uint4 u; } p;
    p.h[0] = (h16)a.x; p.h[1] = (h16)a.y; p.h[2] = (h16)a.z; p.h[3] = (h16)a.w;
    p.h[4] = (h16)b.x; p.h[5] = (h16)b.y; p.h[6] = (h16)b.z; p.h[7] = (h16)b.w;
    return p.u;
}

template <bool A_F16, int OUT_MODE>
__device__ __forceinline__ void mfma_gemm_tile_t(
    const void* __restrict__ Av, const float* __restrict__ W,
    const float* __restrict__ bias, void* __restrict__ outv,
    int m0, int j0, float oscale, h16* aT, h16* bT)
{
    const int tid  = threadIdx.x;
    const int lane = tid & 63;
    const int wid  = tid >> 6;
    const int wr   = wid >> 1;
    const int wc   = wid & 1;
    const int r    = lane & 15;
    const int g    = lane >> 4;

    f32x4 acc[4][2];
    #pragma unroll
    for (int i = 0; i < 4; ++i)
        #pragma unroll
        for (int j = 0; j < 2; ++j)
            acc[i][j] = (f32x4){0.f, 0.f, 0.f, 0.f};

    const int arow  = tid >> 1;
    const int ahalf = (tid & 1) * 16;
    const int brow  = (tid & 127) >> 1;
    const bool doB  = tid < 128;

    for (int k0 = 0; k0 < DIM; k0 += GBK) {
        if constexpr (A_F16) {
            const h16* A = (const h16*)Av;
            const h16* src = A + (size_t)(m0 + arow) * DIM + k0 + ahalf;
            *(uint4*)(aT + arow * GPITCH + ahalf + 0) = *(const uint4*)(src + 0);
            *(uint4*)(aT + arow * GPITCH + ahalf + 8) = *(const uint4*)(src + 8);
        } else {
            const float* A = (const float*)Av;
            const float* src = A + (size_t)(m0 + arow) * DIM + k0 + ahalf;
            const float4 u0 = *(const float4*)(src + 0);
            const float4 u1 = *(const float4*)(src + 4);
            const float4 u2 = *(const float4*)(src + 8);
            const float4 u3 = *(const float4*)(src + 12);
            *(uint4*)(aT + arow * GPITCH + ahalf + 0) = cvt8(u0, u1);
            *(uint4*)(aT + arow * GPITCH + ahalf + 8) = cvt8(u2, u3);
        }
        if (doB) {
            const float* src = W + (size_t)(j0 + brow) * DIM + k0 + ahalf;
            const float4 u0 = *(const float4*)(src + 0);
            const float4 u1 = *(const float4*)(src + 4);
            const float4 u2 = *(const float4*)(src + 8);
            const float4 u3 = *(const float4*)(src + 12);
            *(uint4*)(bT + brow * GPITCH + ahalf + 0) = cvt8(u0, u1);
            *(uint4*)(bT + brow * GPITCH + ahalf + 8) = cvt8(u2, u3);
        }
        __syncthreads();

        half8 af[4], bf[2];
        #pragma unroll
        for (int fr = 0; fr < 4; ++fr)
            af[fr] = *(const half8*)(aT + (wr * 64 + fr * 16 + r) * GPITCH + g * 8);
        #pragma unroll
        for (int fc = 0; fc < 2; ++fc)
            bf[fc] = *(const half8*)(bT + (wc * 32 + fc * 16 + r) * GPITCH + g * 8);

        #pragma unroll
        for (int fr = 0; fr < 4; ++fr)
            #pragma unroll
            for (int fc = 0; fc < 2; ++fc)
                acc[fr][fc] = __builtin_amdgcn_mfma_f32_16x16x32_f16(
                    af[fr], bf[fc], acc[fr][fc], 0, 0, 0);
        __syncthreads();
    }

    #pragma unroll
    for (int fr = 0; fr < 4; ++fr) {
        #pragma unroll
        for (int fc = 0; fc < 2; ++fc) {
            const int col = j0 + wc * 32 + fc * 16 + r;
            const float badd = bias ? bias[col] : 0.f;
            if constexpr (OUT_MODE == 4) {
                // blocked V: 4 acc values = 4 consecutive tokens -> one uint2.
                const int hd = col >> 5, d = col & 31;
                const int rowb = m0 + wr * 64 + fr * 16 + g * 4;
                union { h16 h[4]; uint2 u; } p;
                #pragma unroll
                for (int i = 0; i < 4; ++i) p.h[i] = (h16)(acc[fr][fc][i] * oscale);
                h16* dst = (h16*)outv + ((size_t)hd * 512 + (rowb >> 4)) * 512
                           + d * 16 + (rowb & 15);
                *(uint2*)dst = p.u;
            } else if constexpr (OUT_MODE == 3) {
                const int hd = col >> 5, d = col & 31;
                #pragma unroll
                for (int i = 0; i < 4; ++i) {
                    const int row = m0 + wr * 64 + fr * 16 + g * 4 + i;
                    ((h16*)outv)[((size_t)hd * NTOK + row) * DH + d] =
                        (h16)(acc[fr][fc][i] * oscale);
                }
            } else {
                #pragma unroll
                for (int i = 0; i < 4; ++i) {
                    const int row = m0 + wr * 64 + fr * 16 + g * 4 + i;
                    ((float*)outv)[(size_t)row * INNER + col] =
                        acc[fr][fc][i] * oscale + badd;
                }
            }
        }
    }
}

// ---------------------------------------------------------------------------
// Kernel 1: projections. q (pre-scaled), k -> head-major f16 [2][8][NTOK][32];
// v -> blocked vTb[head][512][32][16].
// ---------------------------------------------------------------------------
__global__ __launch_bounds__(256) void proj_kernel(
    const float* __restrict__ x, const float* __restrict__ q,
    const float* __restrict__ wq, const float* __restrict__ wk,
    const float* __restrict__ wv, h16* __restrict__ qk, h16* __restrict__ vtb)
{
    __shared__ h16 aT[GBM * GPITCH];
    __shared__ h16 bT[GBN * GPITCH];

    const int seg = blockIdx.y >> 2;
    const int jt  = blockIdx.y & 3;
    const float* A = (seg == 0) ? q : x;
    const float* W = (seg == 0) ? wq : ((seg == 1) ? wk : wv);

    if (seg == 2) {
        mfma_gemm_tile_t<false, 4>(A, W, nullptr, vtb, blockIdx.x * GBM, jt * GBN,
                                   1.0f, aT, bT);
    } else {
        h16* outp = qk + (size_t)seg * HEADS * NTOK * DH;
        const float sc = (seg == 0) ? QSCALE : 1.0f;
        mfma_gemm_tile_t<false, 3>(A, W, nullptr, outp, blockIdx.x * GBM, jt * GBN,
                                   sc, aT, bT);
    }
}

// ---------------------------------------------------------------------------
// Kernel 2: zero-LDS, zero-barrier MFMA local attention.
// One wave owns one (row, head) unit: 16 QK tiles (15 runs + 1 masked pad),
// single-pass in-register softmax, 8 PV chunks. grid = 1024 x 256 thr
// (4 waves = 4 independent units). All K loads 1KB-contiguous (head-major),
// all V loads dense 16-line (blocked vTb). launch_bounds(256,3): cap 168.
// ---------------------------------------------------------------------------
__global__ __launch_bounds__(256, 3) void attn_kernel(
    const h16* __restrict__ qk, const h16* __restrict__ vtb, h16* __restrict__ ao)
{
    const int tid  = threadIdx.x;
    const int lane = tid & 63;
    const int wid  = __builtin_amdgcn_readfirstlane(tid >> 6);
    const int xr   = blockIdx.x;
    const int blk  = ((xr & 7) << 7) | (xr >> 3);    // XCD swizzle (1024 = 8*128)
    const int gid  = blk * 4 + wid;                  // 0..4095
    const int head = gid & 7;
    const int r    = gid >> 3;                       // 0..511
    const int h = r & 31, s = (r >> 5) & 7, b = r >> 8;
    const int n_base = r * 16;
    const int c = lane & 15, g = lane >> 4;

    const h16* qb = qk + (size_t)head * NTOK * DH;
    const h16* kb = qk + (size_t)(HEADS + head) * NTOK * DH;
    const h16* vb = vtb + (size_t)head * VHSTRIDE;

    // ---- per-run scalars (wave-uniform) -----------------------------------
    int   tokb[16];
    float kill[16];
    #pragma unroll
    for (int t = 0; t < 16; ++t) {
        const int ds = t / 5, hh = t - 5 * ds;       // t=15 -> ds=3 (pad run)
        const int s2 = s + ds - 1;
        const int h2 = h + hh - 2;
        const bool inb = (t < 15) && ((unsigned)s2 < 8u) && ((unsigned)h2 < 32u);
        const int s2c = min(max(s2, 0), 7);
        const int h2c = min(max(h2, 0), 31);
        tokb[t] = ((b * 8 + s2c) * 32 + h2c) * 16;   // always a valid token base
        kill[t] = inb ? __builtin_inff() : -1e30f;
    }

    // ---- Q fragment -------------------------------------------------------
    const half8 qf = *(const half8*)(qb + (size_t)(n_base + c) * DH + g * 8);

    // ---- QK (swapped): dots[t][i] = S[halo w2 = 4g+i][q = c], run t -------
    f32x4 dots[16];
    #pragma unroll
    for (int t = 0; t < 16; ++t) {
        const half8 kf = *(const half8*)(kb + (size_t)(tokb[t] + c) * DH + g * 8);
        dots[t] = __builtin_amdgcn_mfma_f32_16x16x32_f16(
            kf, qf, (f32x4){0.f, 0.f, 0.f, 0.f}, 0, 0, 0);
    }

    // ---- prefetch V d-tile 0 for all 8 chunks (dense 16-line loads) -------
    // chunk ch = runs (2ch, 2ch+1); lane(c,g): sel = g>>1 picks run,
    // (g&1)*8 the token group; d = c.
    union u4h8 { uint4 u4; half8 hv; } vpre0[8];
    #pragma unroll
    for (int ch = 0; ch < 8; ++ch) {
        const int bv = tokb[2 * ch + (g >> 1)] >> 4;
        vpre0[ch].u4 = *(const uint4*)(vb + (size_t)bv * 512 + c * 16 + (g & 1) * 8);
    }

    // ---- mask + max -------------------------------------------------------
    float mx = -1e30f;
    #pragma unroll
    for (int t = 0; t < 16; ++t) {
        const float kl = kill[t];
        #pragma unroll
        for (int i = 0; i < 4; ++i) {
            const int w2 = 4 * g + i;
            const bool okw = ((unsigned)(w2 - c + 2) <= 4u);   // |w2-c| <= 2
            float dv = okw ? dots[t][i] : -1e30f;
            dv = fminf(dv, kl);
            dots[t][i] = dv;
            mx = fmaxf(mx, dv);
        }
    }
    mx = fmaxf(mx, __shfl_xor(mx, 16));
    mx = fmaxf(mx, __shfl_xor(mx, 32));

    // ---- exp + sum + pack (unnormalized P, f16) ---------------------------
    float sum = 0.f;
    int d0[16], d1[16];
    #pragma unroll
    for (int t = 0; t < 16; ++t) {
        const float e0v = __expf(dots[t][0] - mx);
        const float e1v = __expf(dots[t][1] - mx);
        const float e2v = __expf(dots[t][2] - mx);
        const float e3v = __expf(dots[t][3] - mx);
        sum += (e0v + e1v) + (e2v + e3v);
        union { h16 hh2[2]; int u; } p0, p1;
        p0.hh2[0] = (h16)e0v; p0.hh2[1] = (h16)e1v;
        p1.hh2[0] = (h16)e2v; p1.hh2[1] = (h16)e3v;
        d0[t] = p0.u; d1[t] = p1.u;
    }
    sum += __shfl_xor(sum, 16);
    sum += __shfl_xor(sum, 32);
    const float inv = 1.f / sum;              // for q = c

    // stats for the q-rows this lane will write (q = 4g+i): lane 4g+i holds
    // inv for q = 4g+i (its c = 4g+i, g = 0).
    float invq[4];
    #pragma unroll
    for (int i = 0; i < 4; ++i) invq[i] = __shfl(inv, 4 * g + i);

    // ---- PV: 8 chunks; A-frag via shfl (R6-validated), B d-tile1 JIT ------
    f32x4 o0 = (f32x4){0.f,0.f,0.f,0.f};
    f32x4 o1 = (f32x4){0.f,0.f,0.f,0.f};
    const bool hi = lane >= 32;
    const int l1 = ((lane & 16) ? 32 : 0) + c;
    const int l2 = l1 + 16;

    #pragma unroll
    for (int ch = 0; ch < 8; ++ch) {
        const int w0a = __shfl(d0[2*ch], l1), w0b = __shfl(d0[2*ch+1], l1);
        const int w1a = __shfl(d1[2*ch], l1), w1b = __shfl(d1[2*ch+1], l1);
        const int w2a = __shfl(d0[2*ch], l2), w2b = __shfl(d0[2*ch+1], l2);
        const int w3a = __shfl(d1[2*ch], l2), w3b = __shfl(d1[2*ch+1], l2);
        union { int u[4]; half8 hv; } pf;
        pf.u[0] = hi ? w0b : w0a;
        pf.u[1] = hi ? w1b : w1a;
        pf.u[2] = hi ? w2b : w2a;
        pf.u[3] = hi ? w3b : w3a;

        const int bv = tokb[2 * ch + (g >> 1)] >> 4;
        union u4h8 v1;
        v1.u4 = *(const uint4*)(vb + (size_t)bv * 512 + (c + 16) * 16 + (g & 1) * 8);

        o0 = __builtin_amdgcn_mfma_f32_16x16x32_f16(pf.hv, vpre0[ch].hv, o0, 0, 0, 0);
        o1 = __builtin_amdgcn_mfma_f32_16x16x32_f16(pf.hv, v1.hv, o1, 0, 0, 0);
    }

    // ---- write (normalize by the target q's sum) --------------------------
    #pragma unroll
    for (int i = 0; i < 4; ++i) {
        const size_t row = (size_t)(n_base + 4 * g + i) * INNER + head * DH;
        ao[row + c]      = (h16)(o0[i] * invq[i]);
        ao[row + 16 + c] = (h16)(o1[i] * invq[i]);
    }
}

// ---------------------------------------------------------------------------
// Kernel 3: out = ao(f16) @ wo^T + bo   grid = (64, 4)   (unchanged)
// ---------------------------------------------------------------------------
__global__ __launch_bounds__(256) void outproj_kernel(
    const h16* __restrict__ ao, const float* __restrict__ wo,
    const float* __restrict__ bo, float* __restrict__ out)
{
    __shared__ h16 aT[GBM * GPITCH];
    __shared__ h16 bT[GBN * GPITCH];
    mfma_gemm_tile_t<true, 0>(ao, wo, bo, out, blockIdx.x * GBM, blockIdx.y * GBN,
                              1.0f, aT, bT);
}

// ---------------------------------------------------------------------------
extern "C" void kernel_launch(void* const* d_in, const int* in_sizes, int n_in,
                              void* d_out, int out_size, void* d_ws, size_t ws_size,
                              hipStream_t stream) {
    const float* x  = (const float*)d_in[0];
    const float* q  = (const float*)d_in[1];
    const float* wq = (const float*)d_in[2];
    const float* wk = (const float*)d_in[3];
    const float* wv = (const float*)d_in[4];
    const float* wo = (const float*)d_in[5];
    const float* bo = (const float*)d_in[6];
    float* out = (float*)d_out;

    // ws: qk f16 [2][8][NTOK][32] (8MB) + vtb f16 [8][512][32][16] (4MB) + ao (4MB)
    h16* qk  = (h16*)d_ws;
    h16* vtb = qk + (size_t)2 * HEADS * NTOK * DH;
    h16* ao  = vtb + (size_t)HEADS * VHSTRIDE;

    dim3 g1(NTOK / GBM, 12);
    proj_kernel<<<g1, 256, 0, stream>>>(x, q, wq, wk, wv, qk, vtb);

    attn_kernel<<<1024, 256, 0, stream>>>(qk, vtb, ao);

    dim3 g3(NTOK / GBM, INNER / GBN);
    outproj_kernel<<<g3, 256, 0, stream>>>(ao, wo, bo, out);
}